// Round 1
// baseline (405.615 us; speedup 1.0000x reference)
//
#include <hip/hip_runtime.h>
#include <math.h>

#define B 32
#define T 1024
#define AC 20
#define SE 16
#define H 64
#define NH 4
#define HD 16
#define NROW (B*T)      // 32768
#define BH (B*NH)       // 128

// ---- workspace layout (float offsets) ----
#define SZ_QKV (BH*T*HD)          // 2,097,152 per tensor
#define OFF_Q   0
#define OFF_K   (OFF_Q + SZ_QKV)
#define OFF_V   (OFF_K + SZ_QKV)
#define OFF_CTX (OFF_V + SZ_QKV)          // [NROW][H]
#define OFF_ET  (OFF_CTX + (size_t)NROW*H)   // enhanced transposed [AC][NROW]
#define OFF_AT  (OFF_ET + (size_t)AC*NROW)   // acoustic transposed [AC][NROW]
#define OFF_WF  (OFF_AT + (size_t)AC*NROW)   // fused weights, 5076 floats
#define OFF_ACC (OFF_WF + 5120)              // 80 floats

// fused-weight sub-offsets inside wf
#define WF_WQ 0
#define WF_BQ 1024
#define WF_WK 1088
#define WF_BK 2368
#define WF_WV 2432
#define WF_BV 3712
#define WF_WO 3776
#define WF_BO 5056
#define WF_TOTAL 5076

__device__ __forceinline__ float4 f4mul(float4 a, float4 b) {
    return make_float4(a.x*b.x, a.y*b.y, a.z*b.z, a.w*b.w);
}
__device__ __forceinline__ float4 f4fma4(float4 a, float4 b, float4 c) {
    c.x += a.x*b.x; c.y += a.y*b.y; c.z += a.z*b.z; c.w += a.w*b.w; return c;
}
__device__ __forceinline__ float4 f4fma(float p, float4 v, float4 a) {
    a.x += p*v.x; a.y += p*v.y; a.z += p*v.z; a.w += p*v.w; return a;
}

// ---------------- K0: fuse weights ----------------
// WqF = 0.25 * in_w[:H] @ Wq          (64x16), bqF = 0.25*(in_w[:H]@bq + in_b[:H])
// WkF = in_w[H:2H] @ Wkv[:H]          (64x20), bkF = in_w[H:2H]@bkv[:H] + in_b[H:2H]
// WvF = in_w[2H:] @ Wkv[H:]           (64x20), bvF likewise
// WoF = proj_w @ out_w                (20x64), boF = proj_w@out_b + proj_b
__global__ __launch_bounds__(256) void k_fuse(
    const float* __restrict__ Wq, const float* __restrict__ bq,
    const float* __restrict__ Wkv, const float* __restrict__ bkv,
    const float* __restrict__ in_w, const float* __restrict__ in_b,
    const float* __restrict__ out_w, const float* __restrict__ out_b,
    const float* __restrict__ proj_w, const float* __restrict__ proj_b,
    float* __restrict__ wf) {
    int idx = blockIdx.x * 256 + threadIdx.x;
    if (idx >= WF_TOTAL) return;
    if (idx < WF_BQ) {                       // WqF[i][j]
        int i = idx >> 4, j = idx & 15;
        float s = 0.f;
        for (int m = 0; m < H; ++m) s += in_w[i*H + m] * Wq[m*SE + j];
        wf[idx] = 0.25f * s;
    } else if (idx < WF_WK) {                // bqF
        int i = idx - WF_BQ;
        float s = in_b[i];
        for (int m = 0; m < H; ++m) s += in_w[i*H + m] * bq[m];
        wf[idx] = 0.25f * s;
    } else if (idx < WF_BK) {                // WkF[i][j]
        int r = idx - WF_WK; int i = r / AC, j = r % AC;
        float s = 0.f;
        for (int m = 0; m < H; ++m) s += in_w[(H+i)*H + m] * Wkv[m*AC + j];
        wf[idx] = s;
    } else if (idx < WF_WV) {                // bkF
        int i = idx - WF_BK;
        float s = in_b[H + i];
        for (int m = 0; m < H; ++m) s += in_w[(H+i)*H + m] * bkv[m];
        wf[idx] = s;
    } else if (idx < WF_BV) {                // WvF[i][j]
        int r = idx - WF_WV; int i = r / AC, j = r % AC;
        float s = 0.f;
        for (int m = 0; m < H; ++m) s += in_w[(2*H+i)*H + m] * Wkv[(H+m)*AC + j];
        wf[idx] = s;
    } else if (idx < WF_WO) {                // bvF
        int i = idx - WF_BV;
        float s = in_b[2*H + i];
        for (int m = 0; m < H; ++m) s += in_w[(2*H+i)*H + m] * bkv[H + m];
        wf[idx] = s;
    } else if (idx < WF_BO) {                // WoF[c][d]
        int r = idx - WF_WO; int c = r >> 6, d = r & 63;
        float s = 0.f;
        for (int m = 0; m < H; ++m) s += proj_w[c*H + m] * out_w[m*H + d];
        wf[idx] = s;
    } else {                                 // boF
        int c = idx - WF_BO;
        float s = proj_b[c];
        for (int m = 0; m < H; ++m) s += proj_w[c*H + m] * out_b[m];
        wf[idx] = s;
    }
}

// ---------------- K1: fused QKV projection ----------------
// Q/K/V layout: [bh][t][hd]  (bh = b*NH + h), head h takes cols h*16..h*16+15
__global__ __launch_bounds__(256) void k_qkv(
    const float* __restrict__ sem, const float* __restrict__ acst,
    const float* __restrict__ wf,
    float* __restrict__ Q, float* __restrict__ K, float* __restrict__ V) {
    int row = blockIdx.x * 256 + threadIdx.x;   // < 32768
    int b = row >> 10, t = row & 1023;
    float s[SE];
    const float4* sp = (const float4*)(sem + (size_t)row * SE);
    #pragma unroll
    for (int i = 0; i < 4; ++i) {
        float4 v = sp[i];
        s[4*i] = v.x; s[4*i+1] = v.y; s[4*i+2] = v.z; s[4*i+3] = v.w;
    }
    float a[AC];
    const float4* ap = (const float4*)(acst + (size_t)row * AC);
    #pragma unroll
    for (int i = 0; i < 5; ++i) {
        float4 v = ap[i];
        a[4*i] = v.x; a[4*i+1] = v.y; a[4*i+2] = v.z; a[4*i+3] = v.w;
    }
    const float* WqF = wf + WF_WQ; const float* bqF = wf + WF_BQ;
    const float* WkF = wf + WF_WK; const float* bkF = wf + WF_BK;
    const float* WvF = wf + WF_WV; const float* bvF = wf + WF_BV;
    float o[H];
    // Q
    #pragma unroll
    for (int d = 0; d < H; ++d) {
        float acc = bqF[d];
        #pragma unroll
        for (int j = 0; j < SE; ++j) acc += s[j] * WqF[d*SE + j];
        o[d] = acc;
    }
    #pragma unroll
    for (int h = 0; h < NH; ++h) {
        float4* dst = (float4*)(Q + (((size_t)(b*NH + h) * T + t) * HD));
        #pragma unroll
        for (int i = 0; i < 4; ++i)
            dst[i] = make_float4(o[h*16+4*i], o[h*16+4*i+1], o[h*16+4*i+2], o[h*16+4*i+3]);
    }
    // K
    #pragma unroll
    for (int d = 0; d < H; ++d) {
        float acc = bkF[d];
        #pragma unroll
        for (int j = 0; j < AC; ++j) acc += a[j] * WkF[d*AC + j];
        o[d] = acc;
    }
    #pragma unroll
    for (int h = 0; h < NH; ++h) {
        float4* dst = (float4*)(K + (((size_t)(b*NH + h) * T + t) * HD));
        #pragma unroll
        for (int i = 0; i < 4; ++i)
            dst[i] = make_float4(o[h*16+4*i], o[h*16+4*i+1], o[h*16+4*i+2], o[h*16+4*i+3]);
    }
    // V
    #pragma unroll
    for (int d = 0; d < H; ++d) {
        float acc = bvF[d];
        #pragma unroll
        for (int j = 0; j < AC; ++j) acc += a[j] * WvF[d*AC + j];
        o[d] = acc;
    }
    #pragma unroll
    for (int h = 0; h < NH; ++h) {
        float4* dst = (float4*)(V + (((size_t)(b*NH + h) * T + t) * HD));
        #pragma unroll
        for (int i = 0; i < 4; ++i)
            dst[i] = make_float4(o[h*16+4*i], o[h*16+4*i+1], o[h*16+4*i+2], o[h*16+4*i+3]);
    }
}

// ---------------- K2: attention (flash-style, no max needed: |s| << 1) ----------------
// grid 256: blockIdx = bh*2 + half; 256 threads, 2 query rows/thread
__global__ __launch_bounds__(256) void k_attn(
    const float* __restrict__ Q, const float* __restrict__ K,
    const float* __restrict__ V, float* __restrict__ ctx) {
    __shared__ float4 Kt[256];   // 64 keys x 16 f32
    __shared__ float4 Vt[256];
    int tid = threadIdx.x;
    int bh = blockIdx.x >> 1;
    int half = blockIdx.x & 1;
    int r0 = half * 512 + tid * 2;
    const float4* Qb = (const float4*)(Q + (size_t)bh * T * HD);
    const float4* Kb = (const float4*)(K + (size_t)bh * T * HD);
    const float4* Vb = (const float4*)(V + (size_t)bh * T * HD);
    float4 q0[4], q1[4];
    #pragma unroll
    for (int i = 0; i < 4; ++i) { q0[i] = Qb[r0*4 + i]; q1[i] = Qb[r0*4 + 4 + i]; }
    float4 acc0[4], acc1[4];
    #pragma unroll
    for (int i = 0; i < 4; ++i) {
        acc0[i] = make_float4(0.f,0.f,0.f,0.f);
        acc1[i] = make_float4(0.f,0.f,0.f,0.f);
    }
    float l0 = 0.f, l1 = 0.f;
    for (int kt = 0; kt < T; kt += 64) {
        __syncthreads();
        Kt[tid] = Kb[kt*4 + tid];
        Vt[tid] = Vb[kt*4 + tid];
        __syncthreads();
        #pragma unroll 8
        for (int j = 0; j < 64; ++j) {
            float4 k0 = Kt[j*4+0], k1 = Kt[j*4+1], k2 = Kt[j*4+2], k3 = Kt[j*4+3];
            float4 t0 = f4mul(q0[0], k0); t0 = f4fma4(q0[1], k1, t0);
            t0 = f4fma4(q0[2], k2, t0);   t0 = f4fma4(q0[3], k3, t0);
            float4 t1 = f4mul(q1[0], k0); t1 = f4fma4(q1[1], k1, t1);
            t1 = f4fma4(q1[2], k2, t1);   t1 = f4fma4(q1[3], k3, t1);
            float s0 = (t0.x + t0.y) + (t0.z + t0.w);
            float s1 = (t1.x + t1.y) + (t1.z + t1.w);
            float p0 = __expf(s0), p1 = __expf(s1);
            l0 += p0; l1 += p1;
            float4 v0 = Vt[j*4+0], v1 = Vt[j*4+1], v2 = Vt[j*4+2], v3 = Vt[j*4+3];
            acc0[0] = f4fma(p0, v0, acc0[0]); acc0[1] = f4fma(p0, v1, acc0[1]);
            acc0[2] = f4fma(p0, v2, acc0[2]); acc0[3] = f4fma(p0, v3, acc0[3]);
            acc1[0] = f4fma(p1, v0, acc1[0]); acc1[1] = f4fma(p1, v1, acc1[1]);
            acc1[2] = f4fma(p1, v2, acc1[2]); acc1[3] = f4fma(p1, v3, acc1[3]);
        }
    }
    float inv0 = 1.f / l0, inv1 = 1.f / l1;
    int b = bh >> 2, h = bh & 3;
    float4* c0 = (float4*)(ctx + ((size_t)(b*T + r0)     * H + h*HD));
    float4* c1 = (float4*)(ctx + ((size_t)(b*T + r0 + 1) * H + h*HD));
    #pragma unroll
    for (int i = 0; i < 4; ++i) {
        c0[i] = make_float4(acc0[i].x*inv0, acc0[i].y*inv0, acc0[i].z*inv0, acc0[i].w*inv0);
        c1[i] = make_float4(acc1[i].x*inv1, acc1[i].y*inv1, acc1[i].z*inv1, acc1[i].w*inv1);
    }
}

// ---------------- K3: output proj + residual; writes enh & acoustic TRANSPOSED ----------------
__global__ __launch_bounds__(256) void k_proj(
    const float* __restrict__ ctx, const float* __restrict__ acst,
    const float* __restrict__ wf, const float* __restrict__ rlogit,
    float* __restrict__ enhT, float* __restrict__ aT) {
    int row = blockIdx.x * 256 + threadIdx.x;
    const float* WoF = wf + WF_WO;
    const float* boF = wf + WF_BO;
    float sg = 1.f / (1.f + __expf(-rlogit[0]));
    float c[H];
    const float4* cp = (const float4*)(ctx + (size_t)row * H);
    #pragma unroll
    for (int i = 0; i < 16; ++i) {
        float4 v = cp[i];
        c[4*i] = v.x; c[4*i+1] = v.y; c[4*i+2] = v.z; c[4*i+3] = v.w;
    }
    float a[AC];
    const float4* ap = (const float4*)(acst + (size_t)row * AC);
    #pragma unroll
    for (int i = 0; i < 5; ++i) {
        float4 v = ap[i];
        a[4*i] = v.x; a[4*i+1] = v.y; a[4*i+2] = v.z; a[4*i+3] = v.w;
    }
    #pragma unroll
    for (int ch = 0; ch < AC; ++ch) {
        float s = boF[ch];
        #pragma unroll
        for (int d = 0; d < H; ++d) s += c[d] * WoF[ch*H + d];
        float e = a[ch] + sg * s;
        enhT[(size_t)ch * NROW + row] = e;
        aT[(size_t)ch * NROW + row]  = a[ch];
    }
}

// ---------------- K4: per-channel global stats (deterministic, no atomics) ----------------
__global__ __launch_bounds__(256) void k_stats(
    const float* __restrict__ aT, const float* __restrict__ enhT,
    float* __restrict__ accum) {
    int c = blockIdx.x, tid = threadIdx.x;
    const float* ac = aT  + (size_t)c * NROW;
    const float* ec = enhT + (size_t)c * NROW;
    float sa = 0.f, qa = 0.f, se = 0.f, qe = 0.f;
    for (int r = tid; r < NROW; r += 256) {
        float a = ac[r]; sa += a; qa += a*a;
        float e = ec[r]; se += e; qe += e*e;
    }
    #pragma unroll
    for (int off = 32; off > 0; off >>= 1) {
        sa += __shfl_down(sa, off);
        qa += __shfl_down(qa, off);
        se += __shfl_down(se, off);
        qe += __shfl_down(qe, off);
    }
    __shared__ float rs[4][4];
    int w = tid >> 6;
    if ((tid & 63) == 0) { rs[w][0] = sa; rs[w][1] = qa; rs[w][2] = se; rs[w][3] = qe; }
    __syncthreads();
    if (tid == 0) {
        float A = 0.f, QA = 0.f, E = 0.f, QE = 0.f;
        for (int i = 0; i < 4; ++i) { A += rs[i][0]; QA += rs[i][1]; E += rs[i][2]; QE += rs[i][3]; }
        accum[c*4+0] = A; accum[c*4+1] = QA; accum[c*4+2] = E; accum[c*4+3] = QE;
    }
}

// ---------------- K5: std-correction + LayerNorm ----------------
__global__ __launch_bounds__(256) void k_final(
    const float* __restrict__ enhT, const float* __restrict__ accum,
    const float* __restrict__ gamma, const float* __restrict__ beta,
    float* __restrict__ out) {
    int row = blockIdx.x * 256 + threadIdx.x;
    const float Nf = (float)NROW;
    float ef[AC];
    #pragma unroll
    for (int c = 0; c < AC; ++c) {
        float sa = accum[c*4+0], qa = accum[c*4+1];
        float se = accum[c*4+2], qe = accum[c*4+3];
        float mu  = sa / Nf;
        float va  = (qa - sa*sa/Nf) / (Nf - 1.f);
        float sda = sqrtf(fmaxf(va, 0.f));
        float osd = sda + 1e-8f;
        float ve  = (qe - se*se/Nf) / (Nf - 1.f);
        float sde = sqrtf(fmaxf(ve, 0.f));
        float ratio = (sde / osd) / (sda / osd + 1e-8f);
        float corr  = (ratio < 0.4f) ? (0.4f / ratio) : 1.f;
        float e = enhT[(size_t)c * NROW + row];
        ef[c] = (e - mu) * corr + mu;
    }
    float m = 0.f;
    #pragma unroll
    for (int c = 0; c < AC; ++c) m += ef[c];
    m *= (1.f / AC);
    float v = 0.f;
    #pragma unroll
    for (int c = 0; c < AC; ++c) { float d = ef[c] - m; v += d*d; }
    v *= (1.f / AC);
    float inv = rsqrtf(v + 1e-5f);
    float o[AC];
    #pragma unroll
    for (int c = 0; c < AC; ++c) o[c] = (ef[c] - m) * inv * gamma[c] + beta[c];
    float4* op = (float4*)(out + (size_t)row * AC);
    #pragma unroll
    for (int i = 0; i < 5; ++i)
        op[i] = make_float4(o[4*i], o[4*i+1], o[4*i+2], o[4*i+3]);
}

extern "C" void kernel_launch(void* const* d_in, const int* in_sizes, int n_in,
                              void* d_out, int out_size, void* d_ws, size_t ws_size,
                              hipStream_t stream) {
    (void)in_sizes; (void)n_in; (void)out_size; (void)ws_size;
    const float* acoustic = (const float*)d_in[0];
    const float* semantic = (const float*)d_in[1];
    const float* Wq     = (const float*)d_in[2];
    const float* bq     = (const float*)d_in[3];
    const float* Wkv    = (const float*)d_in[4];
    const float* bkv    = (const float*)d_in[5];
    const float* in_w   = (const float*)d_in[6];
    const float* in_b   = (const float*)d_in[7];
    const float* out_w  = (const float*)d_in[8];
    const float* out_b  = (const float*)d_in[9];
    const float* proj_w = (const float*)d_in[10];
    const float* proj_b = (const float*)d_in[11];
    const float* rlogit = (const float*)d_in[12];
    const float* gamma  = (const float*)d_in[13];
    const float* beta   = (const float*)d_in[14];
    float* ws  = (float*)d_ws;
    float* Q   = ws + OFF_Q;
    float* K   = ws + OFF_K;
    float* V   = ws + OFF_V;
    float* ctx = ws + OFF_CTX;
    float* enhT = ws + OFF_ET;
    float* aT   = ws + OFF_AT;
    float* wf   = ws + OFF_WF;
    float* accum = ws + OFF_ACC;
    float* out = (float*)d_out;

    k_fuse<<<(WF_TOTAL + 255)/256, 256, 0, stream>>>(Wq, bq, Wkv, bkv, in_w, in_b,
                                                     out_w, out_b, proj_w, proj_b, wf);
    k_qkv<<<NROW/256, 256, 0, stream>>>(semantic, acoustic, wf, Q, K, V);
    k_attn<<<BH*2, 256, 0, stream>>>(Q, K, V, ctx);
    k_proj<<<NROW/256, 256, 0, stream>>>(ctx, acoustic, wf, rlogit, enhT, aT);
    k_stats<<<AC, 256, 0, stream>>>(aT, enhT, accum);
    k_final<<<NROW/256, 256, 0, stream>>>(enhT, accum, gamma, beta, out);
}

// Round 3
// 269.310 us; speedup vs baseline: 1.5061x; 1.5061x over previous
//
#include <hip/hip_runtime.h>
#include <hip/hip_bf16.h>
#include <math.h>

#define B 32
#define T 1024
#define AC 20
#define SE 16
#define H 64
#define NH 4
#define HD 16
#define NROW (B*T)      // 32768
#define BH (B*NH)       // 128
#define KS 2            // key-split factor
#define KSLICE (T/KS)   // 512
#define NCH (KSLICE/32) // 16 chunks of 32 keys

typedef unsigned short u16;
typedef short short8 __attribute__((ext_vector_type(8)));
typedef float floatx4 __attribute__((ext_vector_type(4)));

// ---- workspace layout (float offsets) ----
#define F_QB   (BH*T*16/2)                   // bf16 tensor of BH*T*16 elems in float units
#define OFF_QB   0
#define OFF_KB   (OFF_QB + F_QB)
#define OFF_VT   (OFF_KB + F_QB)             // bf16 Vt [bh][hd][t'] slot-interleaved
#define OFF_PART (OFF_VT + F_QB)             // f32 [KS][bh][t][16]
#define OFF_PARTL (OFF_PART + KS*BH*T*16)    // f32 [KS][bh][t]
#define OFF_ET   (OFF_PARTL + KS*BH*T)
#define OFF_AT   (OFF_ET + AC*NROW)
#define OFF_WF   (OFF_AT + AC*NROW)
#define OFF_PST  (OFF_WF + 5120)
#define OFF_ACC  (OFF_PST + 20*16*4)

// fused-weight sub-offsets inside wf
#define WF_WQ 0
#define WF_BQ 1024
#define WF_WK 1088
#define WF_BK 2368
#define WF_WV 2432
#define WF_BV 3712
#define WF_WO 3776
#define WF_BO 5056
#define WF_TOTAL 5076

__device__ __forceinline__ u16 bf16b(float a) {
    __hip_bfloat16 t = __float2bfloat16(a);
    u16 u; __builtin_memcpy(&u, &t, 2); return u;
}
__device__ __forceinline__ unsigned packbf(float a, float b) {
    return (unsigned)bf16b(a) | ((unsigned)bf16b(b) << 16);
}

// ---------------- K0: fuse weights ----------------
__global__ __launch_bounds__(256) void k_fuse(
    const float* __restrict__ Wq, const float* __restrict__ bq,
    const float* __restrict__ Wkv, const float* __restrict__ bkv,
    const float* __restrict__ in_w, const float* __restrict__ in_b,
    const float* __restrict__ out_w, const float* __restrict__ out_b,
    const float* __restrict__ proj_w, const float* __restrict__ proj_b,
    float* __restrict__ wf) {
    int idx = blockIdx.x * 256 + threadIdx.x;
    if (idx >= WF_TOTAL) return;
    if (idx < WF_BQ) {                       // WqF[i][j] (scale 0.25 folded)
        int i = idx >> 4, j = idx & 15;
        float s = 0.f;
        for (int m = 0; m < H; ++m) s += in_w[i*H + m] * Wq[m*SE + j];
        wf[idx] = 0.25f * s;
    } else if (idx < WF_WK) {                // bqF
        int i = idx - WF_BQ;
        float s = in_b[i];
        for (int m = 0; m < H; ++m) s += in_w[i*H + m] * bq[m];
        wf[idx] = 0.25f * s;
    } else if (idx < WF_BK) {                // WkF[i][j]
        int r = idx - WF_WK; int i = r / AC, j = r % AC;
        float s = 0.f;
        for (int m = 0; m < H; ++m) s += in_w[(H+i)*H + m] * Wkv[m*AC + j];
        wf[idx] = s;
    } else if (idx < WF_WV) {                // bkF
        int i = idx - WF_BK;
        float s = in_b[H + i];
        for (int m = 0; m < H; ++m) s += in_w[(H+i)*H + m] * bkv[m];
        wf[idx] = s;
    } else if (idx < WF_BV) {                // WvF[i][j]
        int r = idx - WF_WV; int i = r / AC, j = r % AC;
        float s = 0.f;
        for (int m = 0; m < H; ++m) s += in_w[(2*H+i)*H + m] * Wkv[(H+m)*AC + j];
        wf[idx] = s;
    } else if (idx < WF_WO) {                // bvF
        int i = idx - WF_BV;
        float s = in_b[2*H + i];
        for (int m = 0; m < H; ++m) s += in_w[(2*H+i)*H + m] * bkv[H + m];
        wf[idx] = s;
    } else if (idx < WF_BO) {                // WoF[c][d]
        int r = idx - WF_WO; int c = r >> 6, d = r & 63;
        float s = 0.f;
        for (int m = 0; m < H; ++m) s += proj_w[c*H + m] * out_w[m*H + d];
        wf[idx] = s;
    } else {                                 // boF
        int c = idx - WF_BO;
        float s = proj_b[c];
        for (int m = 0; m < H; ++m) s += proj_w[c*H + m] * out_b[m];
        wf[idx] = s;
    }
}

// ---------------- K1: fused QKV projection -> bf16 Q/K + transposed interleaved V ----------------
__global__ __launch_bounds__(128) void k_qkv(
    const float* __restrict__ sem, const float* __restrict__ acst,
    const float* __restrict__ wf,
    u16* __restrict__ Qb, u16* __restrict__ Kb, u16* __restrict__ Vtb) {
    __shared__ __align__(16) float w[WF_TOTAL];
    for (int i = threadIdx.x; i < WF_TOTAL; i += 128) w[i] = wf[i];
    __syncthreads();
    int row = blockIdx.x * 128 + threadIdx.x;
    int b = row >> 10, t = row & 1023;
    float s[SE];
    const float4* sp = (const float4*)(sem + (size_t)row * SE);
    #pragma unroll
    for (int i = 0; i < 4; ++i) {
        float4 v = sp[i];
        s[4*i] = v.x; s[4*i+1] = v.y; s[4*i+2] = v.z; s[4*i+3] = v.w;
    }
    float a[AC];
    const float4* ap = (const float4*)(acst + (size_t)row * AC);
    #pragma unroll
    for (int i = 0; i < 5; ++i) {
        float4 v = ap[i];
        a[4*i] = v.x; a[4*i+1] = v.y; a[4*i+2] = v.z; a[4*i+3] = v.w;
    }
    float o[H];
    // ---- Q ----
    #pragma unroll
    for (int d = 0; d < H; ++d) {
        float acc = w[WF_BQ + d];
        #pragma unroll
        for (int j = 0; j < 4; ++j) {
            float4 wq = *(const float4*)&w[WF_WQ + d*SE + 4*j];
            acc += s[4*j]*wq.x + s[4*j+1]*wq.y + s[4*j+2]*wq.z + s[4*j+3]*wq.w;
        }
        o[d] = acc;
    }
    #pragma unroll
    for (int h = 0; h < NH; ++h) {
        unsigned* dst = (unsigned*)(Qb + (((size_t)(b*NH + h))*T + t)*16);
        #pragma unroll
        for (int i = 0; i < 8; ++i) dst[i] = packbf(o[h*16 + 2*i], o[h*16 + 2*i + 1]);
    }
    // ---- K ----
    #pragma unroll
    for (int d = 0; d < H; ++d) {
        float acc = w[WF_BK + d];
        #pragma unroll
        for (int j = 0; j < 5; ++j) {
            float4 wk = *(const float4*)&w[WF_WK + d*AC + 4*j];
            acc += a[4*j]*wk.x + a[4*j+1]*wk.y + a[4*j+2]*wk.z + a[4*j+3]*wk.w;
        }
        o[d] = acc;
    }
    #pragma unroll
    for (int h = 0; h < NH; ++h) {
        unsigned* dst = (unsigned*)(Kb + (((size_t)(b*NH + h))*T + t)*16);
        #pragma unroll
        for (int i = 0; i < 8; ++i) dst[i] = packbf(o[h*16 + 2*i], o[h*16 + 2*i + 1]);
    }
    // ---- V (transposed, 32-key chunks slot-interleaved: tile0->even, tile1->odd) ----
    #pragma unroll
    for (int d = 0; d < H; ++d) {
        float acc = w[WF_BV + d];
        #pragma unroll
        for (int j = 0; j < 5; ++j) {
            float4 wv = *(const float4*)&w[WF_WV + d*AC + 4*j];
            acc += a[4*j]*wv.x + a[4*j+1]*wv.y + a[4*j+2]*wv.z + a[4*j+3]*wv.w;
        }
        o[d] = acc;
    }
    int w32 = t & 31;
    int slot = (w32 < 16) ? (w32*2) : ((w32-16)*2 + 1);
    int tp = (t & ~31) | slot;
    #pragma unroll
    for (int h = 0; h < NH; ++h)
        #pragma unroll
        for (int d = 0; d < HD; ++d)
            Vtb[((size_t)(b*NH + h)*16 + d)*T + tp] = bf16b(o[h*16 + d]);
}

// ---------------- K2: MFMA flash attention ----------------
// block = 4 waves; wave = 16 q-rows x 512-key slice; grid = bh*16qb*2ks = 4096
#define KPAD 24    // u16 per K LDS row (48 B, 16B-aligned, 2-way banks)
#define VROW 528   // u16 per Vt LDS row (1056 B)
__global__ __launch_bounds__(256) void k_attn(
    const u16* __restrict__ Qb, const u16* __restrict__ Kb, const u16* __restrict__ Vtb,
    float* __restrict__ part, float* __restrict__ partL) {
    __shared__ __align__(16) u16 Ks[KSLICE*KPAD];   // 24.0 KB
    __shared__ __align__(16) u16 Vs[16*VROW];       // 16.5 KB
    __shared__ __align__(16) u16 Ps[4*16*40];       //  5.0 KB (per-wave 16x40)
    const int tid = threadIdx.x;
    const int blk = blockIdx.x;
    const int ks = blk & 1;
    const int qb = (blk >> 1) & 15;
    const int bh = blk >> 5;
    const int kbase = ks * KSLICE;
    // stage K rows [key][16 bf16] and Vt rows [hd][512 bf16]
    {
        const uint4* src = (const uint4*)(Kb + ((size_t)bh*T + kbase)*16);
        for (int r = tid; r < KSLICE; r += 256) {
            uint4 a0 = src[2*r], a1 = src[2*r + 1];
            *(uint4*)&Ks[r*KPAD]     = a0;
            *(uint4*)&Ks[r*KPAD + 8] = a1;
        }
        for (int i = tid; i < 16*(KSLICE/8); i += 256) {
            int d = i >> 6, c = i & 63;
            uint4 v = *(const uint4*)(Vtb + ((size_t)(bh*16 + d))*T + kbase + c*8);
            *(uint4*)&Vs[d*VROW + c*8] = v;
        }
    }
    __syncthreads();
    const int wv = tid >> 6, lane = tid & 63;
    const int col = lane & 15, quad = lane >> 4;
    const int q0 = qb*64 + wv*16;
    short8 qf = {0,0,0,0,0,0,0,0};
    if (quad < 2)
        qf = *(const short8*)(Qb + ((size_t)bh*T + q0 + col)*16 + quad*8);
    const floatx4 z4 = {0.f,0.f,0.f,0.f};
    floatx4 acc = z4;
    float ls[4] = {0.f,0.f,0.f,0.f};
    u16* Pw = &Ps[wv*640];
    for (int ch = 0; ch < NCH; ++ch) {
        short8 kf0 = {0,0,0,0,0,0,0,0}, kf1 = {0,0,0,0,0,0,0,0};
        if (quad < 2) {
            kf0 = *(const short8*)&Ks[(ch*32 + col)*KPAD + quad*8];
            kf1 = *(const short8*)&Ks[(ch*32 + 16 + col)*KPAD + quad*8];
        }
        floatx4 s0 = __builtin_amdgcn_mfma_f32_16x16x32_bf16(qf, kf0, z4, 0, 0, 0);
        floatx4 s1 = __builtin_amdgcn_mfma_f32_16x16x32_bf16(qf, kf1, z4, 0, 0, 0);
        float p0[4], p1[4];
        #pragma unroll
        for (int r = 0; r < 4; ++r) {
            p0[r] = __expf(s0[r]); p1[r] = __expf(s1[r]);
            ls[r] += p0[r] + p1[r];
        }
        #pragma unroll
        for (int r = 0; r < 4; ++r)
            *(unsigned*)&Pw[(quad*4 + r)*40 + col*2] = packbf(p0[r], p1[r]);
        short8 pf = *(const short8*)&Pw[col*40 + quad*8];
        short8 vf = *(const short8*)&Vs[col*VROW + ch*32 + quad*8];
        acc = __builtin_amdgcn_mfma_f32_16x16x32_bf16(pf, vf, acc, 0, 0, 0);
    }
    float* dst = part + (((size_t)ks*BH + bh)*T + q0)*16;
    #pragma unroll
    for (int r = 0; r < 4; ++r) dst[(quad*4 + r)*16 + col] = acc[r];
    #pragma unroll
    for (int m = 1; m < 16; m <<= 1) {
        #pragma unroll
        for (int r = 0; r < 4; ++r) ls[r] += __shfl_xor(ls[r], m);
    }
    if (col == 0) {
        float* ld = partL + ((size_t)ks*BH + bh)*T + q0 + quad*4;
        #pragma unroll
        for (int r = 0; r < 4; ++r) ld[r] = ls[r];
    }
}

// ---------------- K3: combine partials + output proj + residual; writes transposed ----------------
__global__ __launch_bounds__(128) void k_proj(
    const float* __restrict__ part, const float* __restrict__ partL,
    const float* __restrict__ acst, const float* __restrict__ wf,
    const float* __restrict__ rlogit,
    float* __restrict__ enhT, float* __restrict__ aT) {
    __shared__ __align__(16) float w[AC*H + AC];
    for (int i = threadIdx.x; i < AC*H + AC; i += 128) w[i] = wf[WF_WO + i];
    __syncthreads();
    int row = blockIdx.x * 128 + threadIdx.x;
    int b = row >> 10, t = row & 1023;
    float c[H];
    #pragma unroll
    for (int h = 0; h < NH; ++h) {
        int bh = b*NH + h;
        float l = partL[(size_t)bh*T + t] + partL[(size_t)(BH + bh)*T + t];
        float inv = 1.f / l;
        const float4* pa = (const float4*)(part + ((size_t)bh*T + t)*16);
        const float4* pb = (const float4*)(part + ((size_t)(BH + bh)*T + t)*16);
        #pragma unroll
        for (int i = 0; i < 4; ++i) {
            float4 x = pa[i], y = pb[i];
            c[h*16+4*i+0] = (x.x + y.x)*inv;
            c[h*16+4*i+1] = (x.y + y.y)*inv;
            c[h*16+4*i+2] = (x.z + y.z)*inv;
            c[h*16+4*i+3] = (x.w + y.w)*inv;
        }
    }
    float a[AC];
    const float4* ap = (const float4*)(acst + (size_t)row * AC);
    #pragma unroll
    for (int i = 0; i < 5; ++i) {
        float4 v = ap[i];
        a[4*i] = v.x; a[4*i+1] = v.y; a[4*i+2] = v.z; a[4*i+3] = v.w;
    }
    float sg = 1.f / (1.f + __expf(-rlogit[0]));
    #pragma unroll
    for (int ch = 0; ch < AC; ++ch) {
        float s = w[AC*H + ch];
        #pragma unroll
        for (int j = 0; j < 16; ++j) {
            float4 wo = *(const float4*)&w[ch*H + 4*j];
            s += c[4*j]*wo.x + c[4*j+1]*wo.y + c[4*j+2]*wo.z + c[4*j+3]*wo.w;
        }
        float e = a[ch] + sg * s;
        enhT[(size_t)ch * NROW + row] = e;
        aT[(size_t)ch * NROW + row]  = a[ch];
    }
}

// ---------------- K4a: per-channel partial stats ----------------
__global__ __launch_bounds__(256) void k_stats1(
    const float* __restrict__ aT, const float* __restrict__ enhT,
    float* __restrict__ pst) {
    int c = blockIdx.x >> 4, sl = blockIdx.x & 15;
    int base = sl * (NROW/16);
    const float* ac = aT  + (size_t)c*NROW + base;
    const float* ec = enhT + (size_t)c*NROW + base;
    float sa = 0.f, qa = 0.f, se = 0.f, qe = 0.f;
    for (int r = threadIdx.x; r < NROW/16; r += 256) {
        float a = ac[r]; sa += a; qa += a*a;
        float e = ec[r]; se += e; qe += e*e;
    }
    #pragma unroll
    for (int off = 32; off > 0; off >>= 1) {
        sa += __shfl_down(sa, off);
        qa += __shfl_down(qa, off);
        se += __shfl_down(se, off);
        qe += __shfl_down(qe, off);
    }
    __shared__ float rs[4][4];
    int w = threadIdx.x >> 6;
    if ((threadIdx.x & 63) == 0) { rs[w][0] = sa; rs[w][1] = qa; rs[w][2] = se; rs[w][3] = qe; }
    __syncthreads();
    if (threadIdx.x == 0) {
        float A = 0.f, QA = 0.f, E = 0.f, QE = 0.f;
        for (int i = 0; i < 4; ++i) { A += rs[i][0]; QA += rs[i][1]; E += rs[i][2]; QE += rs[i][3]; }
        float* d = pst + (size_t)(c*16 + sl)*4;
        d[0] = A; d[1] = QA; d[2] = E; d[3] = QE;
    }
}

// ---------------- K4b: combine partial stats ----------------
__global__ __launch_bounds__(128) void k_stats2(
    const float* __restrict__ pst, float* __restrict__ accum) {
    int i = threadIdx.x;
    if (i < 80) {
        int c = i >> 2, j = i & 3;
        float s = 0.f;
        for (int sl = 0; sl < 16; ++sl) s += pst[(size_t)(c*16 + sl)*4 + j];
        accum[i] = s;
    }
}

// ---------------- K5: std-correction + LayerNorm ----------------
__global__ __launch_bounds__(128) void k_final(
    const float* __restrict__ enhT, const float* __restrict__ accum,
    const float* __restrict__ gamma, const float* __restrict__ beta,
    float* __restrict__ out) {
    int row = blockIdx.x * 128 + threadIdx.x;
    const float Nf = (float)NROW;
    float ef[AC];
    #pragma unroll
    for (int c = 0; c < AC; ++c) {
        float sa = accum[c*4+0], qa = accum[c*4+1];
        float se = accum[c*4+2], qe = accum[c*4+3];
        float mu  = sa / Nf;
        float va  = (qa - sa*sa/Nf) / (Nf - 1.f);
        float sda = sqrtf(fmaxf(va, 0.f));
        float osd = sda + 1e-8f;
        float ve  = (qe - se*se/Nf) / (Nf - 1.f);
        float sde = sqrtf(fmaxf(ve, 0.f));
        float ratio = (sde / osd) / (sda / osd + 1e-8f);
        float corr  = (ratio < 0.4f) ? (0.4f / ratio) : 1.f;
        float e = enhT[(size_t)c * NROW + row];
        ef[c] = (e - mu) * corr + mu;
    }
    float m = 0.f;
    #pragma unroll
    for (int c = 0; c < AC; ++c) m += ef[c];
    m *= (1.f / AC);
    float v = 0.f;
    #pragma unroll
    for (int c = 0; c < AC; ++c) { float d = ef[c] - m; v += d*d; }
    v *= (1.f / AC);
    float inv = rsqrtf(v + 1e-5f);
    float o[AC];
    #pragma unroll
    for (int c = 0; c < AC; ++c) o[c] = (ef[c] - m) * inv * gamma[c] + beta[c];
    float4* op = (float4*)(out + (size_t)row * AC);
    #pragma unroll
    for (int i = 0; i < 5; ++i)
        op[i] = make_float4(o[4*i], o[4*i+1], o[4*i+2], o[4*i+3]);
}

extern "C" void kernel_launch(void* const* d_in, const int* in_sizes, int n_in,
                              void* d_out, int out_size, void* d_ws, size_t ws_size,
                              hipStream_t stream) {
    (void)in_sizes; (void)n_in; (void)out_size; (void)ws_size;
    const float* acoustic = (const float*)d_in[0];
    const float* semantic = (const float*)d_in[1];
    const float* Wq     = (const float*)d_in[2];
    const float* bq     = (const float*)d_in[3];
    const float* Wkv    = (const float*)d_in[4];
    const float* bkv    = (const float*)d_in[5];
    const float* in_w   = (const float*)d_in[6];
    const float* in_b   = (const float*)d_in[7];
    const float* out_w  = (const float*)d_in[8];
    const float* out_b  = (const float*)d_in[9];
    const float* proj_w = (const float*)d_in[10];
    const float* proj_b = (const float*)d_in[11];
    const float* rlogit = (const float*)d_in[12];
    const float* gamma  = (const float*)d_in[13];
    const float* beta   = (const float*)d_in[14];
    float* ws = (float*)d_ws;
    u16* Qb  = (u16*)(ws + OFF_QB);
    u16* Kb  = (u16*)(ws + OFF_KB);
    u16* Vtb = (u16*)(ws + OFF_VT);
    float* part  = ws + OFF_PART;
    float* partL = ws + OFF_PARTL;
    float* enhT  = ws + OFF_ET;
    float* aT    = ws + OFF_AT;
    float* wf    = ws + OFF_WF;
    float* pst   = ws + OFF_PST;
    float* accum = ws + OFF_ACC;
    float* out = (float*)d_out;

    k_fuse<<<(WF_TOTAL + 255)/256, 256, 0, stream>>>(Wq, bq, Wkv, bkv, in_w, in_b,
                                                     out_w, out_b, proj_w, proj_b, wf);
    k_qkv<<<NROW/128, 128, 0, stream>>>(semantic, acoustic, wf, Qb, Kb, Vtb);
    k_attn<<<BH*16*KS, 256, 0, stream>>>(Qb, Kb, Vtb, part, partL);
    k_proj<<<NROW/128, 128, 0, stream>>>(part, partL, acoustic, wf, rlogit, enhT, aT);
    k_stats1<<<AC*16, 256, 0, stream>>>(aT, enhT, pst);
    k_stats2<<<1, 128, 0, stream>>>(pst, accum);
    k_final<<<NROW/128, 128, 0, stream>>>(enhT, accum, gamma, beta, out);
}

// Round 4
// 169.317 us; speedup vs baseline: 2.3956x; 1.5906x over previous
//
#include <hip/hip_runtime.h>
#include <hip/hip_bf16.h>
#include <math.h>

#define B 32
#define T 1024
#define AC 20
#define SE 16
#define H 64
#define NH 4
#define HD 16
#define NROW (B*T)      // 32768
#define BH (B*NH)       // 128
#define KS 2            // key-split factor
#define KSLICE (T/KS)   // 512
#define NCH (KSLICE/32) // 16 chunks of 32 keys

typedef unsigned short u16;
typedef short short8 __attribute__((ext_vector_type(8)));
typedef float floatx4 __attribute__((ext_vector_type(4)));

// ---- workspace layout (float offsets) ----
#define F_QB   (BH*T*16/2)                   // bf16 tensor of BH*T*16 elems in float units
#define OFF_QB   0
#define OFF_KB   (OFF_QB + F_QB)
#define OFF_VT   (OFF_KB + F_QB)             // bf16 Vt [bh][hd][t'] slot-interleaved
#define OFF_PART (OFF_VT + F_QB)             // f32 [KS][bh][t][16]
#define OFF_PARTL (OFF_PART + KS*BH*T*16)    // f32 [KS][bh][t]
#define OFF_ET   (OFF_PARTL + KS*BH*T)
#define OFF_AT   (OFF_ET + AC*NROW)
#define OFF_WF   (OFF_AT + AC*NROW)
#define OFF_PST  (OFF_WF + 5120)
#define OFF_ACC  (OFF_PST + 20*16*4)

// fused-weight sub-offsets inside wf
#define WF_WQ 0
#define WF_BQ 1024
#define WF_WK 1088
#define WF_BK 2368
#define WF_WV 2432
#define WF_BV 3712
#define WF_WO 3776
#define WF_BO 5056
#define WF_TOTAL 5076

__device__ __forceinline__ u16 bf16b(float a) {
    __hip_bfloat16 t = __float2bfloat16(a);
    u16 u; __builtin_memcpy(&u, &t, 2); return u;
}
__device__ __forceinline__ unsigned packbf(float a, float b) {
    return (unsigned)bf16b(a) | ((unsigned)bf16b(b) << 16);
}

// ---------------- K0: fuse weights ----------------
__global__ __launch_bounds__(256) void k_fuse(
    const float* __restrict__ Wq, const float* __restrict__ bq,
    const float* __restrict__ Wkv, const float* __restrict__ bkv,
    const float* __restrict__ in_w, const float* __restrict__ in_b,
    const float* __restrict__ out_w, const float* __restrict__ out_b,
    const float* __restrict__ proj_w, const float* __restrict__ proj_b,
    float* __restrict__ wf) {
    int idx = blockIdx.x * 256 + threadIdx.x;
    if (idx >= WF_TOTAL) return;
    if (idx < WF_BQ) {                       // WqF[i][j] (scale 0.25 folded)
        int i = idx >> 4, j = idx & 15;
        float s = 0.f;
        for (int m = 0; m < H; ++m) s += in_w[i*H + m] * Wq[m*SE + j];
        wf[idx] = 0.25f * s;
    } else if (idx < WF_WK) {                // bqF
        int i = idx - WF_BQ;
        float s = in_b[i];
        for (int m = 0; m < H; ++m) s += in_w[i*H + m] * bq[m];
        wf[idx] = 0.25f * s;
    } else if (idx < WF_BK) {                // WkF[i][j]
        int r = idx - WF_WK; int i = r / AC, j = r % AC;
        float s = 0.f;
        for (int m = 0; m < H; ++m) s += in_w[(H+i)*H + m] * Wkv[m*AC + j];
        wf[idx] = s;
    } else if (idx < WF_WV) {                // bkF
        int i = idx - WF_BK;
        float s = in_b[H + i];
        for (int m = 0; m < H; ++m) s += in_w[(H+i)*H + m] * bkv[m];
        wf[idx] = s;
    } else if (idx < WF_BV) {                // WvF[i][j]
        int r = idx - WF_WV; int i = r / AC, j = r % AC;
        float s = 0.f;
        for (int m = 0; m < H; ++m) s += in_w[(2*H+i)*H + m] * Wkv[(H+m)*AC + j];
        wf[idx] = s;
    } else if (idx < WF_WO) {                // bvF
        int i = idx - WF_BV;
        float s = in_b[2*H + i];
        for (int m = 0; m < H; ++m) s += in_w[(2*H+i)*H + m] * bkv[H + m];
        wf[idx] = s;
    } else if (idx < WF_BO) {                // WoF[c][d]
        int r = idx - WF_WO; int c = r >> 6, d = r & 63;
        float s = 0.f;
        for (int m = 0; m < H; ++m) s += proj_w[c*H + m] * out_w[m*H + d];
        wf[idx] = s;
    } else {                                 // boF
        int c = idx - WF_BO;
        float s = proj_b[c];
        for (int m = 0; m < H; ++m) s += proj_w[c*H + m] * out_b[m];
        wf[idx] = s;
    }
}

// ---------------- K1: fused QKV projection (wave-specialized, 12 sections/row) ----------------
// block = 192 threads = 16 rows x 12 sections; wave0=Q(4 heads), wave1=K, wave2=V
__global__ __launch_bounds__(192) void k_qkv(
    const float* __restrict__ sem, const float* __restrict__ acst,
    const float* __restrict__ wf,
    u16* __restrict__ Qb, u16* __restrict__ Kb, u16* __restrict__ Vtb) {
    const int tid = threadIdx.x;
    const int sec = tid >> 4, r = tid & 15;
    const int row = blockIdx.x * 16 + r;
    const int b = row >> 10, t = row & 1023;
    const int type = sec >> 2, h = sec & 3;
    float o[16];
    if (type == 0) {
        float s[SE];
        const float4* sp = (const float4*)(sem + (size_t)row * SE);
        #pragma unroll
        for (int i = 0; i < 4; ++i) {
            float4 v = sp[i];
            s[4*i] = v.x; s[4*i+1] = v.y; s[4*i+2] = v.z; s[4*i+3] = v.w;
        }
        const float* wq = wf + WF_WQ + h*16*SE;
        const float* bq = wf + WF_BQ + h*16;
        #pragma unroll
        for (int ii = 0; ii < 16; ++ii) {
            float acc = bq[ii];
            #pragma unroll
            for (int j = 0; j < 4; ++j) {
                float4 w4 = *(const float4*)(wq + ii*SE + 4*j);
                acc += s[4*j]*w4.x + s[4*j+1]*w4.y + s[4*j+2]*w4.z + s[4*j+3]*w4.w;
            }
            o[ii] = acc;
        }
        unsigned* dst = (unsigned*)(Qb + (((size_t)(b*NH + h))*T + t)*16);
        #pragma unroll
        for (int i = 0; i < 8; ++i) dst[i] = packbf(o[2*i], o[2*i+1]);
    } else {
        float a[AC];
        const float4* ap = (const float4*)(acst + (size_t)row * AC);
        #pragma unroll
        for (int i = 0; i < 5; ++i) {
            float4 v = ap[i];
            a[4*i] = v.x; a[4*i+1] = v.y; a[4*i+2] = v.z; a[4*i+3] = v.w;
        }
        const float* wb = wf + (type == 1 ? WF_WK : WF_WV) + h*16*AC;
        const float* bb = wf + (type == 1 ? WF_BK : WF_BV) + h*16;
        #pragma unroll
        for (int ii = 0; ii < 16; ++ii) {
            float acc = bb[ii];
            #pragma unroll
            for (int j = 0; j < 5; ++j) {
                float4 w4 = *(const float4*)(wb + ii*AC + 4*j);
                acc += a[4*j]*w4.x + a[4*j+1]*w4.y + a[4*j+2]*w4.z + a[4*j+3]*w4.w;
            }
            o[ii] = acc;
        }
        if (type == 1) {
            unsigned* dst = (unsigned*)(Kb + (((size_t)(b*NH + h))*T + t)*16);
            #pragma unroll
            for (int i = 0; i < 8; ++i) dst[i] = packbf(o[2*i], o[2*i+1]);
        } else {
            int w32 = t & 31;
            int slot = (w32 < 16) ? (w32*2) : ((w32-16)*2 + 1);
            int tp = (t & ~31) | slot;
            #pragma unroll
            for (int d = 0; d < HD; ++d)
                Vtb[((size_t)(b*NH + h)*16 + d)*T + tp] = bf16b(o[d]);
        }
    }
}

// ---------------- K2: MFMA flash attention ----------------
// block = 4 waves; wave = 16 q-rows x 512-key slice; grid = bh*16qb*2ks = 4096
#define KPAD 24    // u16 per K LDS row (48 B, 16B-aligned, 2-way banks)
#define VROW 528   // u16 per Vt LDS row (1056 B)
__global__ __launch_bounds__(256) void k_attn(
    const u16* __restrict__ Qb, const u16* __restrict__ Kb, const u16* __restrict__ Vtb,
    float* __restrict__ part, float* __restrict__ partL) {
    __shared__ __align__(16) u16 Ks[KSLICE*KPAD];   // 24.0 KB
    __shared__ __align__(16) u16 Vs[16*VROW];       // 16.5 KB
    __shared__ __align__(16) u16 Ps[4*16*40];       //  5.0 KB (per-wave 16x40)
    const int tid = threadIdx.x;
    const int blk = blockIdx.x;
    const int ks = blk & 1;
    const int qb = (blk >> 1) & 15;
    const int bh = blk >> 5;
    const int kbase = ks * KSLICE;
    // stage K rows [key][16 bf16] and Vt rows [hd][512 bf16]
    {
        const uint4* src = (const uint4*)(Kb + ((size_t)bh*T + kbase)*16);
        for (int r = tid; r < KSLICE; r += 256) {
            uint4 a0 = src[2*r], a1 = src[2*r + 1];
            *(uint4*)&Ks[r*KPAD]     = a0;
            *(uint4*)&Ks[r*KPAD + 8] = a1;
        }
        for (int i = tid; i < 16*(KSLICE/8); i += 256) {
            int d = i >> 6, c = i & 63;
            uint4 v = *(const uint4*)(Vtb + ((size_t)(bh*16 + d))*T + kbase + c*8);
            *(uint4*)&Vs[d*VROW + c*8] = v;
        }
    }
    __syncthreads();
    const int wv = tid >> 6, lane = tid & 63;
    const int col = lane & 15, quad = lane >> 4;
    const int q0 = qb*64 + wv*16;
    short8 qf = {0,0,0,0,0,0,0,0};
    if (quad < 2)
        qf = *(const short8*)(Qb + ((size_t)bh*T + q0 + col)*16 + quad*8);
    const floatx4 z4 = {0.f,0.f,0.f,0.f};
    floatx4 acc = z4;
    float ls[4] = {0.f,0.f,0.f,0.f};
    u16* Pw = &Ps[wv*640];
    for (int ch = 0; ch < NCH; ++ch) {
        short8 kf0 = {0,0,0,0,0,0,0,0}, kf1 = {0,0,0,0,0,0,0,0};
        if (quad < 2) {
            kf0 = *(const short8*)&Ks[(ch*32 + col)*KPAD + quad*8];
            kf1 = *(const short8*)&Ks[(ch*32 + 16 + col)*KPAD + quad*8];
        }
        floatx4 s0 = __builtin_amdgcn_mfma_f32_16x16x32_bf16(qf, kf0, z4, 0, 0, 0);
        floatx4 s1 = __builtin_amdgcn_mfma_f32_16x16x32_bf16(qf, kf1, z4, 0, 0, 0);
        float p0[4], p1[4];
        #pragma unroll
        for (int r = 0; r < 4; ++r) {
            p0[r] = __expf(s0[r]); p1[r] = __expf(s1[r]);
            ls[r] += p0[r] + p1[r];
        }
        #pragma unroll
        for (int r = 0; r < 4; ++r)
            *(unsigned*)&Pw[(quad*4 + r)*40 + col*2] = packbf(p0[r], p1[r]);
        short8 pf = *(const short8*)&Pw[col*40 + quad*8];
        short8 vf = *(const short8*)&Vs[col*VROW + ch*32 + quad*8];
        acc = __builtin_amdgcn_mfma_f32_16x16x32_bf16(pf, vf, acc, 0, 0, 0);
    }
    float* dst = part + (((size_t)ks*BH + bh)*T + q0)*16;
    #pragma unroll
    for (int r = 0; r < 4; ++r) dst[(quad*4 + r)*16 + col] = acc[r];
    #pragma unroll
    for (int m = 1; m < 16; m <<= 1) {
        #pragma unroll
        for (int r = 0; r < 4; ++r) ls[r] += __shfl_xor(ls[r], m);
    }
    if (col == 0) {
        float* ld = partL + ((size_t)ks*BH + bh)*T + q0 + quad*4;
        #pragma unroll
        for (int r = 0; r < 4; ++r) ld[r] = ls[r];
    }
}

// ---------------- K3: combine partials + output proj + residual (two-phase, 64 rows/block) ----------------
#define CSTR 65
__global__ __launch_bounds__(256) void k_proj(
    const float* __restrict__ part, const float* __restrict__ partL,
    const float* __restrict__ acst, const float* __restrict__ wf,
    const float* __restrict__ rlogit,
    float* __restrict__ enhT, float* __restrict__ aT) {
    __shared__ float ctxs[64*CSTR];                     // 16.6 KB, stride-65 conflict-free
    __shared__ __align__(16) float wsm[AC*H + AC];      // 5.2 KB
    const int tid = threadIdx.x;
    for (int i = tid; i < AC*H + AC; i += 256) wsm[i] = wf[WF_WO + i];
    // ---- phase 1: combine split-K partials -> ctx row chunk in LDS ----
    {
        const int r = tid & 63, h = tid >> 6;
        const int row = blockIdx.x*64 + r;
        const int b = row >> 10, t = row & 1023;
        const int bh = b*NH + h;
        float l = partL[(size_t)bh*T + t] + partL[(size_t)(BH + bh)*T + t];
        float inv = 1.f / l;
        const float4* pa = (const float4*)(part + ((size_t)bh*T + t)*16);
        const float4* pb = (const float4*)(part + ((size_t)(BH + bh)*T + t)*16);
        float* cd = &ctxs[r*CSTR + h*16];
        #pragma unroll
        for (int i = 0; i < 4; ++i) {
            float4 x = pa[i], y = pb[i];
            cd[4*i+0] = (x.x + y.x)*inv;
            cd[4*i+1] = (x.y + y.y)*inv;
            cd[4*i+2] = (x.z + y.z)*inv;
            cd[4*i+3] = (x.w + y.w)*inv;
        }
    }
    __syncthreads();
    // ---- phase 2: 5 output channels per thread ----
    const int r = tid & 63, cg = tid >> 6;
    const int row = blockIdx.x*64 + r;
    float c64[H];
    #pragma unroll
    for (int k = 0; k < H; ++k) c64[k] = ctxs[r*CSTR + k];
    float sg = 1.f / (1.f + __expf(-rlogit[0]));
    #pragma unroll
    for (int j = 0; j < 5; ++j) {
        int ch = cg*5 + j;
        float s = wsm[AC*H + ch];
        const float4* w4 = (const float4*)(wsm + ch*H);
        #pragma unroll
        for (int k = 0; k < 16; ++k) {
            float4 w = w4[k];
            s += c64[4*k]*w.x + c64[4*k+1]*w.y + c64[4*k+2]*w.z + c64[4*k+3]*w.w;
        }
        float a = acst[(size_t)row*AC + ch];
        float e = a + sg * s;
        enhT[(size_t)ch * NROW + row] = e;
        aT[(size_t)ch * NROW + row]  = a;
    }
}

// ---------------- K4a: per-channel partial stats ----------------
__global__ __launch_bounds__(256) void k_stats1(
    const float* __restrict__ aT, const float* __restrict__ enhT,
    float* __restrict__ pst) {
    int c = blockIdx.x >> 4, sl = blockIdx.x & 15;
    int base = sl * (NROW/16);
    const float* ac = aT  + (size_t)c*NROW + base;
    const float* ec = enhT + (size_t)c*NROW + base;
    float sa = 0.f, qa = 0.f, se = 0.f, qe = 0.f;
    for (int r = threadIdx.x; r < NROW/16; r += 256) {
        float a = ac[r]; sa += a; qa += a*a;
        float e = ec[r]; se += e; qe += e*e;
    }
    #pragma unroll
    for (int off = 32; off > 0; off >>= 1) {
        sa += __shfl_down(sa, off);
        qa += __shfl_down(qa, off);
        se += __shfl_down(se, off);
        qe += __shfl_down(qe, off);
    }
    __shared__ float rs[4][4];
    int w = threadIdx.x >> 6;
    if ((threadIdx.x & 63) == 0) { rs[w][0] = sa; rs[w][1] = qa; rs[w][2] = se; rs[w][3] = qe; }
    __syncthreads();
    if (threadIdx.x == 0) {
        float A = 0.f, QA = 0.f, E = 0.f, QE = 0.f;
        for (int i = 0; i < 4; ++i) { A += rs[i][0]; QA += rs[i][1]; E += rs[i][2]; QE += rs[i][3]; }
        float* d = pst + (size_t)(c*16 + sl)*4;
        d[0] = A; d[1] = QA; d[2] = E; d[3] = QE;
    }
}

// ---------------- K4b: combine partial stats ----------------
__global__ __launch_bounds__(128) void k_stats2(
    const float* __restrict__ pst, float* __restrict__ accum) {
    int i = threadIdx.x;
    if (i < 80) {
        int c = i >> 2, j = i & 3;
        float s = 0.f;
        for (int sl = 0; sl < 16; ++sl) s += pst[(size_t)(c*16 + sl)*4 + j];
        accum[i] = s;
    }
}

// ---------------- K5: std-correction + LayerNorm ----------------
__global__ __launch_bounds__(128) void k_final(
    const float* __restrict__ enhT, const float* __restrict__ accum,
    const float* __restrict__ gamma, const float* __restrict__ beta,
    float* __restrict__ out) {
    int row = blockIdx.x * 128 + threadIdx.x;
    const float Nf = (float)NROW;
    float ef[AC];
    #pragma unroll
    for (int c = 0; c < AC; ++c) {
        float sa = accum[c*4+0], qa = accum[c*4+1];
        float se = accum[c*4+2], qe = accum[c*4+3];
        float mu  = sa / Nf;
        float va  = (qa - sa*sa/Nf) / (Nf - 1.f);
        float sda = sqrtf(fmaxf(va, 0.f));
        float osd = sda + 1e-8f;
        float ve  = (qe - se*se/Nf) / (Nf - 1.f);
        float sde = sqrtf(fmaxf(ve, 0.f));
        float ratio = (sde / osd) / (sda / osd + 1e-8f);
        float corr  = (ratio < 0.4f) ? (0.4f / ratio) : 1.f;
        float e = enhT[(size_t)c * NROW + row];
        ef[c] = (e - mu) * corr + mu;
    }
    float m = 0.f;
    #pragma unroll
    for (int c = 0; c < AC; ++c) m += ef[c];
    m *= (1.f / AC);
    float v = 0.f;
    #pragma unroll
    for (int c = 0; c < AC; ++c) { float d = ef[c] - m; v += d*d; }
    v *= (1.f / AC);
    float inv = rsqrtf(v + 1e-5f);
    float o[AC];
    #pragma unroll
    for (int c = 0; c < AC; ++c) o[c] = (ef[c] - m) * inv * gamma[c] + beta[c];
    float4* op = (float4*)(out + (size_t)row * AC);
    #pragma unroll
    for (int i = 0; i < 5; ++i)
        op[i] = make_float4(o[4*i], o[4*i+1], o[4*i+2], o[4*i+3]);
}

extern "C" void kernel_launch(void* const* d_in, const int* in_sizes, int n_in,
                              void* d_out, int out_size, void* d_ws, size_t ws_size,
                              hipStream_t stream) {
    (void)in_sizes; (void)n_in; (void)out_size; (void)ws_size;
    const float* acoustic = (const float*)d_in[0];
    const float* semantic = (const float*)d_in[1];
    const float* Wq     = (const float*)d_in[2];
    const float* bq     = (const float*)d_in[3];
    const float* Wkv    = (const float*)d_in[4];
    const float* bkv    = (const float*)d_in[5];
    const float* in_w   = (const float*)d_in[6];
    const float* in_b   = (const float*)d_in[7];
    const float* out_w  = (const float*)d_in[8];
    const float* out_b  = (const float*)d_in[9];
    const float* proj_w = (const float*)d_in[10];
    const float* proj_b = (const float*)d_in[11];
    const float* rlogit = (const float*)d_in[12];
    const float* gamma  = (const float*)d_in[13];
    const float* beta   = (const float*)d_in[14];
    float* ws = (float*)d_ws;
    u16* Qb  = (u16*)(ws + OFF_QB);
    u16* Kb  = (u16*)(ws + OFF_KB);
    u16* Vtb = (u16*)(ws + OFF_VT);
    float* part  = ws + OFF_PART;
    float* partL = ws + OFF_PARTL;
    float* enhT  = ws + OFF_ET;
    float* aT    = ws + OFF_AT;
    float* wf    = ws + OFF_WF;
    float* pst   = ws + OFF_PST;
    float* accum = ws + OFF_ACC;
    float* out = (float*)d_out;

    k_fuse<<<(WF_TOTAL + 255)/256, 256, 0, stream>>>(Wq, bq, Wkv, bkv, in_w, in_b,
                                                     out_w, out_b, proj_w, proj_b, wf);
    k_qkv<<<NROW/16, 192, 0, stream>>>(semantic, acoustic, wf, Qb, Kb, Vtb);
    k_attn<<<BH*16*KS, 256, 0, stream>>>(Qb, Kb, Vtb, part, partL);
    k_proj<<<NROW/64, 256, 0, stream>>>(part, partL, acoustic, wf, rlogit, enhT, aT);
    k_stats1<<<AC*16, 256, 0, stream>>>(aT, enhT, pst);
    k_stats2<<<1, 128, 0, stream>>>(pst, accum);
    k_final<<<NROW/128, 128, 0, stream>>>(enhT, accum, gamma, beta, out);
}